// Round 1
// baseline (678.496 us; speedup 1.0000x reference)
//
#include <hip/hip_runtime.h>
#include <math.h>

#define NWAVE   8
#define NORBIT  64
#define NATOMS  16384
#define NPAIRS  524288
#define HID     64
#define OC_LOOP 3

// ---------- helpers ----------
__device__ __forceinline__ float wred_sum(float v) {
#pragma unroll
    for (int o = 1; o < 64; o <<= 1) v += __shfl_xor(v, o, 64);
    return v;
}

// LayerNorm (over full 64-lane wave, one value per lane) + SiLU
__device__ __forceinline__ float ln_silu(float h, float gg, float bb) {
    float m = wred_sum(h) * (1.f / 64.f);
    float c = h - m;
    float v = wred_sum(c * c) * (1.f / 64.f);
    float y = c * rsqrtf(v + 1e-5f) * gg + bb;
    return y / (1.f + expf(-y));  // silu
}

// ---------- CSR build (counting sort of pairs by center atom) ----------
__global__ void k_hist(const int* __restrict__ ai0, int* __restrict__ cnt) {
    int p = blockIdx.x * 256 + threadIdx.x;
    if (p < NPAIRS) atomicAdd(&cnt[ai0[p]], 1);
}

__global__ void k_scan(const int* __restrict__ cnt, int* __restrict__ offs,
                       int* __restrict__ cursor) {
    __shared__ int sums[1024];
    int t = threadIdx.x;
    int base = t * 16;
    int v[16];
    int s = 0;
#pragma unroll
    for (int u = 0; u < 16; u++) { v[u] = cnt[base + u]; s += v[u]; }
    sums[t] = s;
    __syncthreads();
    for (int d = 1; d < 1024; d <<= 1) {
        int x = (t >= d) ? sums[t - d] : 0;
        __syncthreads();
        sums[t] += x;
        __syncthreads();
    }
    int run = (t == 0) ? 0 : sums[t - 1];
#pragma unroll
    for (int u = 0; u < 16; u++) {
        offs[base + u] = run;
        cursor[base + u] = run;
        run += v[u];
    }
    if (t == 1023) offs[NATOMS] = run;
}

__global__ void k_scatter(const int* __restrict__ ai0, int* __restrict__ cursor,
                          int* __restrict__ plist) {
    int p = blockIdx.x * 256 + threadIdx.x;
    if (p < NPAIRS) {
        int pos = atomicAdd(&cursor[ai0[p]], 1);
        plist[pos] = p;
    }
}

// ---------- embc MLP per atom: center_coeff[atom][64] ----------
__global__ void k_center(const int* __restrict__ spec,
                         const float* __restrict__ W1, const float* __restrict__ b1,
                         const float* __restrict__ g,  const float* __restrict__ be,
                         const float* __restrict__ W2, const float* __restrict__ b2,
                         float* __restrict__ ccoef) {
    __shared__ float h_s[4][64];
    int lane = threadIdx.x & 63, slot = threadIdx.x >> 6;
    int atom = blockIdx.x * 4 + slot;
    int s = spec[atom] + 1;
    float h = W1[s * 64 + lane] + b1[lane];
    h = ln_silu(h, g[lane], be[lane]);
    h_s[slot][lane] = h;
    __syncthreads();
    float o = b2[lane];
#pragma unroll 8
    for (int i = 0; i < 64; i++) o += h_s[slot][i] * W2[i * 64 + lane];
    ccoef[atom * 64 + lane] = o;
}

// ---------- per-pair: dist_vec (to d_out), ang[4], radial[8], iter0[8] ----------
__global__ void k_pair(const float* __restrict__ cart, const int* __restrict__ aidx,
                       const int* __restrict__ spec,
                       const float* __restrict__ W1, const float* __restrict__ b1,
                       const float* __restrict__ g,  const float* __restrict__ be,
                       const float* __restrict__ W2, const float* __restrict__ b2,
                       float* __restrict__ dist_out, float* __restrict__ ang,
                       float* __restrict__ radial,   float* __restrict__ iter) {
    __shared__ float h_s[4][64];
    __shared__ float ne_s[4][24];
    int lane = threadIdx.x & 63, slot = threadIdx.x >> 6;
    int p = blockIdx.x * 4 + slot;
    int i0 = aidx[p];
    int i1 = aidx[NPAIRS + p];
    float dv0 = cart[i0 * 3 + 0] - cart[i1 * 3 + 0];
    float dv1 = cart[i0 * 3 + 1] - cart[i1 * 3 + 1];
    float dv2 = cart[i0 * 3 + 2] - cart[i1 * 3 + 2];
    float d = sqrtf(dv0 * dv0 + dv1 * dv1 + dv2 * dv2);
    if (lane < 3) dist_out[(size_t)p * 3 + lane] = (lane == 0) ? dv0 : (lane == 1) ? dv1 : dv2;

    int s0 = spec[i0] + 1, s1 = spec[i1] + 1;
    float h = W1[s0 * 64 + lane] + W1[s1 * 64 + lane] + b1[lane];
    h = ln_silu(h, g[lane], be[lane]);
    h_s[slot][lane] = h;
    __syncthreads();
    if (lane < 24) {
        float o = b2[lane];
#pragma unroll 8
        for (int i = 0; i < 64; i++) o += h_s[slot][i] * W2[i * 24 + lane];
        ne_s[slot][lane] = o;
    }
    __syncthreads();

    float cth = cosf(d * (float)(M_PI / 4.0));
    float t0 = 0.5f * cth + 0.5f;
    float fc = t0 * t0;

    if (lane < 8) {
        float alpha = ne_s[slot][8 + lane];
        float mu    = ne_s[slot][16 + lane];
        float t = alpha * (d - mu);
        radial[(size_t)p * 8 + lane] = expf(-t * t);
        iter[(size_t)p * 8 + lane]   = ne_s[slot][lane];
    }
    if (lane < 4) {
        float a = (lane == 0) ? fc : (lane == 1) ? dv0 * fc : (lane == 2) ? dv1 * fc : dv2 * fc;
        ang[(size_t)p * 4 + lane] = a;
    }
}

// ---------- density per atom (wave): co[4][8] gather + contraction ----------
__global__ void k_density(const int* __restrict__ offs, const int* __restrict__ plist,
                          const float* __restrict__ ang, const float* __restrict__ radial,
                          const float* __restrict__ iter, const float* __restrict__ ccoef,
                          const float* __restrict__ cc_l,  // contracted_coeff + l*1024
                          float* __restrict__ density) {
    __shared__ float co_s[4][32];
    int lane = threadIdx.x & 63, slot = threadIdx.x >> 6;
    int atom = blockIdx.x * 4 + slot;
    int start = offs[atom], end = offs[atom + 1];
    int half = lane >> 5, jk = lane & 31;
    int j = jk >> 3, k = jk & 7;
    float acc = 0.f;
    for (int pos = start + half; pos < end; pos += 2) {
        int p = plist[pos];
        acc += ang[(size_t)p * 4 + j] * radial[(size_t)p * 8 + k] * iter[(size_t)p * 8 + k];
    }
    acc += __shfl_xor(acc, 32, 64);
    if (lane < 32) co_s[slot][jk] = acc;
    __syncthreads();

    int m = lane;
    float dens = ccoef[atom * 64 + m];
#pragma unroll
    for (int jj = 0; jj < 4; jj++) {
        int row = (jj > 0) ? 1 : 0;
        float s = 0.f;
#pragma unroll
        for (int kk = 0; kk < 8; kk++)
            s += co_s[slot][jj * 8 + kk] * cc_l[row * 512 + kk * 64 + m];
        dens += s * s;
    }
    density[atom * 64 + m] = dens;
}

// ---------- oc MLP per atom: density(64) -> nnout(8) ----------
__global__ void k_oc(const float* __restrict__ density,
                     const float* __restrict__ W1, const float* __restrict__ b1,
                     const float* __restrict__ g,  const float* __restrict__ be,
                     const float* __restrict__ W2, const float* __restrict__ b2,
                     float* __restrict__ nnout) {
    __shared__ float d_s[4][64];
    __shared__ float h_s[4][64];
    int lane = threadIdx.x & 63, slot = threadIdx.x >> 6;
    int atom = blockIdx.x * 4 + slot;
    float x = density[atom * 64 + lane];
    d_s[slot][lane] = x;
    __syncthreads();
    float h = b1[lane];
#pragma unroll 8
    for (int i = 0; i < 64; i++) h += d_s[slot][i] * W1[i * 64 + lane];
    h = ln_silu(h, g[lane], be[lane]);
    h_s[slot][lane] = h;
    __syncthreads();
    if (lane < 8) {
        float o = b2[lane];
#pragma unroll 8
        for (int i = 0; i < 64; i++) o += h_s[slot][i] * W2[i * 8 + lane];
        nnout[atom * 8 + lane] = o;
    }
}

// ---------- iter_coeff += nnout[neigh] ----------
__global__ void k_upd(const int* __restrict__ ai1, const float* __restrict__ nnout,
                      float* __restrict__ iter) {
    int p = blockIdx.x * 256 + threadIdx.x;
    if (p >= NPAIRS) return;
    int n = ai1[p];
    const float4* src = (const float4*)(nnout + (size_t)n * 8);
    float4* dst = (float4*)(iter + (size_t)p * 8);
    float4 a = src[0], b = src[1];
    float4 x = dst[0], y = dst[1];
    x.x += a.x; x.y += a.y; x.z += a.z; x.w += a.w;
    y.x += b.x; y.y += b.y; y.z += b.z; y.w += b.w;
    dst[0] = x; dst[1] = y;
}

// ---------- out MLP per atom: density(64) -> scalar ----------
__global__ void k_out(const float* __restrict__ density, const int* __restrict__ spec,
                      const float* __restrict__ W1, const float* __restrict__ b1,
                      const float* __restrict__ g,  const float* __restrict__ be,
                      const float* __restrict__ W2, const float* __restrict__ b2,
                      float* __restrict__ out) {
    __shared__ float d_s[4][64];
    int lane = threadIdx.x & 63, slot = threadIdx.x >> 6;
    int atom = blockIdx.x * 4 + slot;
    float x = density[atom * 64 + lane];
    d_s[slot][lane] = x;
    __syncthreads();
    float h = b1[lane];
#pragma unroll 8
    for (int i = 0; i < 64; i++) h += d_s[slot][i] * W1[i * 64 + lane];
    h = ln_silu(h, g[lane], be[lane]);
    float partial = h * W2[lane];
    float s = wred_sum(partial);
    if (lane == 0) {
        float mask = (spec[atom] >= 0) ? 1.f : 0.f;
        out[atom] = (s + b2[0]) * mask;
    }
}

extern "C" void kernel_launch(void* const* d_in, const int* in_sizes, int n_in,
                              void* d_out, int out_size, void* d_ws, size_t ws_size,
                              hipStream_t stream) {
    const float* cart   = (const float*)d_in[0];
    const int*   aidx   = (const int*)d_in[1];
    const int*   spec   = (const int*)d_in[2];
    // d_in[3] = neigh_species (unused by reference)
    const float* ccoeff = (const float*)d_in[4];   // (4,2,8,64)
    const float* embn_W1 = (const float*)d_in[5];
    const float* embn_b1 = (const float*)d_in[6];
    const float* embn_g  = (const float*)d_in[7];
    const float* embn_be = (const float*)d_in[8];
    const float* embn_W2 = (const float*)d_in[9];
    const float* embn_b2 = (const float*)d_in[10];
    const float* embc_W1 = (const float*)d_in[11];
    const float* embc_b1 = (const float*)d_in[12];
    const float* embc_g  = (const float*)d_in[13];
    const float* embc_be = (const float*)d_in[14];
    const float* embc_W2 = (const float*)d_in[15];
    const float* embc_b2 = (const float*)d_in[16];
    const float* oc_W1 = (const float*)d_in[17];   // (3,64,64)
    const float* oc_b1 = (const float*)d_in[18];
    const float* oc_g  = (const float*)d_in[19];
    const float* oc_be = (const float*)d_in[20];
    const float* oc_W2 = (const float*)d_in[21];   // (3,64,8)
    const float* oc_b2 = (const float*)d_in[22];   // (3,8)
    const float* out_W1 = (const float*)d_in[23];
    const float* out_b1 = (const float*)d_in[24];
    const float* out_g  = (const float*)d_in[25];
    const float* out_be = (const float*)d_in[26];
    const float* out_W2 = (const float*)d_in[27];
    const float* out_b2 = (const float*)d_in[28];

    float* outp = (float*)d_out;              // [0, NPAIRS*3) dist_vec, then NATOMS outputs

    // workspace carve (256B aligned)
    char* ws = (char*)d_ws;
    size_t off = 0;
    auto carve = [&](size_t bytes) { size_t o = off; off = (off + bytes + 255) & ~(size_t)255; return o; };
    float* radial  = (float*)(ws + carve((size_t)NPAIRS * 8 * 4));
    float* ang     = (float*)(ws + carve((size_t)NPAIRS * 4 * 4));
    float* iter    = (float*)(ws + carve((size_t)NPAIRS * 8 * 4));
    float* ccenter = (float*)(ws + carve((size_t)NATOMS * 64 * 4));
    float* density = (float*)(ws + carve((size_t)NATOMS * 64 * 4));
    float* nnout   = (float*)(ws + carve((size_t)NATOMS * 8 * 4));
    int*   cnt     = (int*)(ws + carve((size_t)NATOMS * 4));
    int*   offs    = (int*)(ws + carve((size_t)(NATOMS + 1) * 4));
    int*   cursor  = (int*)(ws + carve((size_t)NATOMS * 4));
    int*   plist   = (int*)(ws + carve((size_t)NPAIRS * 4));

    hipMemsetAsync(cnt, 0, (size_t)NATOMS * 4, stream);

    k_hist<<<NPAIRS / 256, 256, 0, stream>>>(aidx, cnt);
    k_scan<<<1, 1024, 0, stream>>>(cnt, offs, cursor);
    k_scatter<<<NPAIRS / 256, 256, 0, stream>>>(aidx, cursor, plist);

    k_center<<<NATOMS / 4, 256, 0, stream>>>(spec, embc_W1, embc_b1, embc_g, embc_be,
                                             embc_W2, embc_b2, ccenter);

    k_pair<<<NPAIRS / 4, 256, 0, stream>>>(cart, aidx, spec, embn_W1, embn_b1, embn_g,
                                           embn_be, embn_W2, embn_b2,
                                           outp, ang, radial, iter);

    k_density<<<NATOMS / 4, 256, 0, stream>>>(offs, plist, ang, radial, iter, ccenter,
                                              ccoeff + 0 * 1024, density);

    for (int l = 0; l < OC_LOOP; l++) {
        k_oc<<<NATOMS / 4, 256, 0, stream>>>(density, oc_W1 + l * 4096, oc_b1 + l * 64,
                                             oc_g + l * 64, oc_be + l * 64,
                                             oc_W2 + l * 512, oc_b2 + l * 8, nnout);
        k_upd<<<NPAIRS / 256, 256, 0, stream>>>(aidx + NPAIRS, nnout, iter);
        k_density<<<NATOMS / 4, 256, 0, stream>>>(offs, plist, ang, radial, iter, ccenter,
                                                  ccoeff + (l + 1) * 1024, density);
    }

    k_out<<<NATOMS / 4, 256, 0, stream>>>(density, spec, out_W1, out_b1, out_g, out_be,
                                          out_W2, out_b2, outp + (size_t)NPAIRS * 3);
}

// Round 2
// 288.144 us; speedup vs baseline: 2.3547x; 2.3547x over previous
//
#include <hip/hip_runtime.h>
#include <math.h>

#define NWAVE   8
#define NORBIT  64
#define NATOMS  16384
#define NPAIRS  524288
#define HID     64
#define OC_LOOP 3
#define NSPEC   117              // species values 0..116
#define TBLN    (NSPEC * NSPEC)  // 13689 unique (s0,s1) combos

// ---------- helpers ----------
__device__ __forceinline__ float wred_sum(float v) {
#pragma unroll
    for (int o = 1; o < 64; o <<= 1) v += __shfl_xor(v, o, 64);
    return v;
}

// LayerNorm (over full 64-lane wave, one value per lane) + SiLU
__device__ __forceinline__ float ln_silu(float h, float gg, float bb) {
    float m = wred_sum(h) * (1.f / 64.f);
    float c = h - m;
    float v = wred_sum(c * c) * (1.f / 64.f);
    float y = c * rsqrtf(v + 1e-5f) * gg + bb;
    return y / (1.f + expf(-y));  // silu
}

// ---------- CSR build (counting sort of pairs by center atom) ----------
__global__ void k_hist(const int* __restrict__ ai0, int* __restrict__ cnt) {
    int p = blockIdx.x * 256 + threadIdx.x;
    if (p < NPAIRS) atomicAdd(&cnt[ai0[p]], 1);
}

__global__ void k_scan(const int* __restrict__ cnt, int* __restrict__ offs,
                       int* __restrict__ cursor) {
    __shared__ int sums[1024];
    int t = threadIdx.x;
    int base = t * 16;
    int v[16];
    int s = 0;
#pragma unroll
    for (int u = 0; u < 16; u++) { v[u] = cnt[base + u]; s += v[u]; }
    sums[t] = s;
    __syncthreads();
    for (int d = 1; d < 1024; d <<= 1) {
        int x = (t >= d) ? sums[t - d] : 0;
        __syncthreads();
        sums[t] += x;
        __syncthreads();
    }
    int run = (t == 0) ? 0 : sums[t - 1];
#pragma unroll
    for (int u = 0; u < 16; u++) {
        offs[base + u] = run;
        cursor[base + u] = run;
        run += v[u];
    }
    if (t == 1023) offs[NATOMS] = run;
}

__global__ void k_scatter(const int* __restrict__ ai0, int* __restrict__ cursor,
                          int* __restrict__ plist) {
    int p = blockIdx.x * 256 + threadIdx.x;
    if (p < NPAIRS) {
        int pos = atomicAdd(&cursor[ai0[p]], 1);
        plist[pos] = p;
    }
}

// ---------- embc MLP per atom: center_coeff[atom][64] ----------
__global__ void k_center(const int* __restrict__ spec,
                         const float* __restrict__ W1, const float* __restrict__ b1,
                         const float* __restrict__ g,  const float* __restrict__ be,
                         const float* __restrict__ W2, const float* __restrict__ b2,
                         float* __restrict__ ccoef) {
    __shared__ float h_s[4][64];
    int lane = threadIdx.x & 63, slot = threadIdx.x >> 6;
    int atom = blockIdx.x * 4 + slot;
    int s = spec[atom] + 1;
    float h = W1[s * 64 + lane] + b1[lane];
    h = ln_silu(h, g[lane], be[lane]);
    h_s[slot][lane] = h;
    __syncthreads();
    float o = b2[lane];
#pragma unroll 8
    for (int i = 0; i < 64; i++) o += h_s[slot][i] * W2[i * 64 + lane];
    ccoef[atom * 64 + lane] = o;
}

// ---------- embn MLP per unique species pair: table[key][24] ----------
__global__ void k_table(const float* __restrict__ W1, const float* __restrict__ b1,
                        const float* __restrict__ g,  const float* __restrict__ be,
                        const float* __restrict__ W2, const float* __restrict__ b2,
                        float* __restrict__ table) {
    __shared__ float h_s[4][64];
    int lane = threadIdx.x & 63, slot = threadIdx.x >> 6;
    int key = blockIdx.x * 4 + slot;
    int kk = (key < TBLN) ? key : 0;    // clamp; whole wave uniform, barrier-safe
    int s0 = kk / NSPEC + 1, s1 = kk % NSPEC + 1;
    float h = W1[s0 * 64 + lane] + W1[s1 * 64 + lane] + b1[lane];
    h = ln_silu(h, g[lane], be[lane]);
    h_s[slot][lane] = h;
    __syncthreads();
    if (lane < 24 && key < TBLN) {
        float o = b2[lane];
#pragma unroll 8
        for (int i = 0; i < 64; i++) o += h_s[slot][i] * W2[i * 24 + lane];
        table[key * 24 + lane] = o;
    }
}

// ---------- per-pair (one THREAD per sorted slot): dist, ang, radial, iter0, neigh ----------
__global__ void k_pair2(const float* __restrict__ cart, const int* __restrict__ aidx,
                        const int* __restrict__ spec,  const float* __restrict__ table,
                        const int* __restrict__ plist,
                        float* __restrict__ dist_out, float* __restrict__ ang,
                        float* __restrict__ radial,   float* __restrict__ it0,
                        int* __restrict__ neigh) {
    int pos = blockIdx.x * 256 + threadIdx.x;
    int p = plist[pos];
    int i0 = aidx[p];
    int i1 = aidx[NPAIRS + p];
    float dv0 = cart[i0 * 3 + 0] - cart[i1 * 3 + 0];
    float dv1 = cart[i0 * 3 + 1] - cart[i1 * 3 + 1];
    float dv2 = cart[i0 * 3 + 2] - cart[i1 * 3 + 2];
    float d = sqrtf(dv0 * dv0 + dv1 * dv1 + dv2 * dv2);
    dist_out[(size_t)p * 3 + 0] = dv0;
    dist_out[(size_t)p * 3 + 1] = dv1;
    dist_out[(size_t)p * 3 + 2] = dv2;

    int key = spec[i0] * NSPEC + spec[i1];
    const float4* ne = (const float4*)(table + (size_t)key * 24);
    float4 it_a = ne[0], it_b = ne[1];      // iter coeff [0:8)
    float4 al_a = ne[2], al_b = ne[3];      // alpha      [8:16)
    float4 mu_a = ne[4], mu_b = ne[5];      // mu         [16:24)

    float cth = cosf(d * (float)(M_PI / 4.0));
    float t0 = 0.5f * cth + 0.5f;
    float fc = t0 * t0;

    float4 av = make_float4(fc, dv0 * fc, dv1 * fc, dv2 * fc);
    *(float4*)(ang + (size_t)pos * 4) = av;

    float4 r_a, r_b;
    float t;
    t = al_a.x * (d - mu_a.x); r_a.x = expf(-t * t);
    t = al_a.y * (d - mu_a.y); r_a.y = expf(-t * t);
    t = al_a.z * (d - mu_a.z); r_a.z = expf(-t * t);
    t = al_a.w * (d - mu_a.w); r_a.w = expf(-t * t);
    t = al_b.x * (d - mu_b.x); r_b.x = expf(-t * t);
    t = al_b.y * (d - mu_b.y); r_b.y = expf(-t * t);
    t = al_b.z * (d - mu_b.z); r_b.z = expf(-t * t);
    t = al_b.w * (d - mu_b.w); r_b.w = expf(-t * t);
    ((float4*)(radial + (size_t)pos * 8))[0] = r_a;
    ((float4*)(radial + (size_t)pos * 8))[1] = r_b;
    ((float4*)(it0 + (size_t)pos * 8))[0] = it_a;
    ((float4*)(it0 + (size_t)pos * 8))[1] = it_b;
    neigh[pos] = i1;
}

// ---------- fused density + oc-MLP per atom (wave). Ping-pong S_in -> S_out ----------
template <bool HAS_S, bool ACC>
__global__ void k_dens_oc(const int* __restrict__ offs,
                          const float* __restrict__ ang, const float* __restrict__ radial,
                          const float* __restrict__ it0, const int* __restrict__ neigh,
                          const float* __restrict__ S_in,
                          const float* __restrict__ ccoef, const float* __restrict__ cc_l,
                          const float* __restrict__ W1, const float* __restrict__ b1,
                          const float* __restrict__ g,  const float* __restrict__ be,
                          const float* __restrict__ W2, const float* __restrict__ b2,
                          float* __restrict__ S_out) {
    __shared__ float co_s[4][32];
    __shared__ float dens_s[4][64];
    __shared__ float h_s[4][64];
    int lane = threadIdx.x & 63, slot = threadIdx.x >> 6;
    int atom = blockIdx.x * 4 + slot;
    int start = offs[atom], end = offs[atom + 1];
    int half = lane >> 5, jk = lane & 31;
    int j = jk >> 3, k = jk & 7;
    float acc = 0.f;
    for (int pos = start + half; pos < end; pos += 2) {
        float a  = ang[(size_t)pos * 4 + j];
        float rk = radial[(size_t)pos * 8 + k];
        float it = it0[(size_t)pos * 8 + k];
        if (HAS_S) it += S_in[(size_t)neigh[pos] * 8 + k];
        acc += a * rk * it;
    }
    acc += __shfl_xor(acc, 32, 64);
    if (lane < 32) co_s[slot][jk] = acc;
    __syncthreads();

    float dens = ccoef[atom * 64 + lane];
#pragma unroll
    for (int jj = 0; jj < 4; jj++) {
        int row = (jj > 0) ? 1 : 0;
        float s = 0.f;
#pragma unroll
        for (int kk = 0; kk < 8; kk++)
            s += co_s[slot][jj * 8 + kk] * cc_l[row * 512 + kk * 64 + lane];
        dens += s * s;
    }
    dens_s[slot][lane] = dens;
    __syncthreads();

    float h = b1[lane];
#pragma unroll 8
    for (int i = 0; i < 64; i++) h += dens_s[slot][i] * W1[i * 64 + lane];
    h = ln_silu(h, g[lane], be[lane]);
    h_s[slot][lane] = h;
    __syncthreads();
    if (lane < 8) {
        float o = b2[lane];
#pragma unroll 8
        for (int i = 0; i < 64; i++) o += h_s[slot][i] * W2[i * 8 + lane];
        if (ACC) o += S_in[(size_t)atom * 8 + lane];
        S_out[(size_t)atom * 8 + lane] = o;
    }
}

// ---------- fused final density + out-MLP per atom (wave) ----------
__global__ void k_dens_out(const int* __restrict__ offs,
                           const float* __restrict__ ang, const float* __restrict__ radial,
                           const float* __restrict__ it0, const int* __restrict__ neigh,
                           const float* __restrict__ S_in,
                           const float* __restrict__ ccoef, const float* __restrict__ cc_l,
                           const int* __restrict__ spec,
                           const float* __restrict__ W1, const float* __restrict__ b1,
                           const float* __restrict__ g,  const float* __restrict__ be,
                           const float* __restrict__ W2, const float* __restrict__ b2,
                           float* __restrict__ out) {
    __shared__ float co_s[4][32];
    __shared__ float dens_s[4][64];
    int lane = threadIdx.x & 63, slot = threadIdx.x >> 6;
    int atom = blockIdx.x * 4 + slot;
    int start = offs[atom], end = offs[atom + 1];
    int half = lane >> 5, jk = lane & 31;
    int j = jk >> 3, k = jk & 7;
    float acc = 0.f;
    for (int pos = start + half; pos < end; pos += 2) {
        float a  = ang[(size_t)pos * 4 + j];
        float rk = radial[(size_t)pos * 8 + k];
        float it = it0[(size_t)pos * 8 + k] + S_in[(size_t)neigh[pos] * 8 + k];
        acc += a * rk * it;
    }
    acc += __shfl_xor(acc, 32, 64);
    if (lane < 32) co_s[slot][jk] = acc;
    __syncthreads();

    float dens = ccoef[atom * 64 + lane];
#pragma unroll
    for (int jj = 0; jj < 4; jj++) {
        int row = (jj > 0) ? 1 : 0;
        float s = 0.f;
#pragma unroll
        for (int kk = 0; kk < 8; kk++)
            s += co_s[slot][jj * 8 + kk] * cc_l[row * 512 + kk * 64 + lane];
        dens += s * s;
    }
    dens_s[slot][lane] = dens;
    __syncthreads();

    float h = b1[lane];
#pragma unroll 8
    for (int i = 0; i < 64; i++) h += dens_s[slot][i] * W1[i * 64 + lane];
    h = ln_silu(h, g[lane], be[lane]);
    float s = wred_sum(h * W2[lane]);
    if (lane == 0) {
        float mask = (spec[atom] >= 0) ? 1.f : 0.f;
        out[atom] = (s + b2[0]) * mask;
    }
}

extern "C" void kernel_launch(void* const* d_in, const int* in_sizes, int n_in,
                              void* d_out, int out_size, void* d_ws, size_t ws_size,
                              hipStream_t stream) {
    const float* cart   = (const float*)d_in[0];
    const int*   aidx   = (const int*)d_in[1];
    const int*   spec   = (const int*)d_in[2];
    const float* ccoeff = (const float*)d_in[4];   // (4,2,8,64)
    const float* embn_W1 = (const float*)d_in[5];
    const float* embn_b1 = (const float*)d_in[6];
    const float* embn_g  = (const float*)d_in[7];
    const float* embn_be = (const float*)d_in[8];
    const float* embn_W2 = (const float*)d_in[9];
    const float* embn_b2 = (const float*)d_in[10];
    const float* embc_W1 = (const float*)d_in[11];
    const float* embc_b1 = (const float*)d_in[12];
    const float* embc_g  = (const float*)d_in[13];
    const float* embc_be = (const float*)d_in[14];
    const float* embc_W2 = (const float*)d_in[15];
    const float* embc_b2 = (const float*)d_in[16];
    const float* oc_W1 = (const float*)d_in[17];   // (3,64,64)
    const float* oc_b1 = (const float*)d_in[18];
    const float* oc_g  = (const float*)d_in[19];
    const float* oc_be = (const float*)d_in[20];
    const float* oc_W2 = (const float*)d_in[21];   // (3,64,8)
    const float* oc_b2 = (const float*)d_in[22];   // (3,8)
    const float* out_W1 = (const float*)d_in[23];
    const float* out_b1 = (const float*)d_in[24];
    const float* out_g  = (const float*)d_in[25];
    const float* out_be = (const float*)d_in[26];
    const float* out_W2 = (const float*)d_in[27];
    const float* out_b2 = (const float*)d_in[28];

    float* outp = (float*)d_out;   // [0, NPAIRS*3) dist_vec, then NATOMS outputs

    // workspace carve (256B aligned)
    char* ws = (char*)d_ws;
    size_t off = 0;
    auto carve = [&](size_t bytes) { size_t o = off; off = (off + bytes + 255) & ~(size_t)255; return o; };
    float* radial  = (float*)(ws + carve((size_t)NPAIRS * 8 * 4));
    float* ang     = (float*)(ws + carve((size_t)NPAIRS * 4 * 4));
    float* it0     = (float*)(ws + carve((size_t)NPAIRS * 8 * 4));
    int*   neigh   = (int*)(ws + carve((size_t)NPAIRS * 4));
    float* ccenter = (float*)(ws + carve((size_t)NATOMS * 64 * 4));
    float* Sa      = (float*)(ws + carve((size_t)NATOMS * 8 * 4));
    float* Sb      = (float*)(ws + carve((size_t)NATOMS * 8 * 4));
    float* table   = (float*)(ws + carve((size_t)TBLN * 24 * 4));
    int*   cnt     = (int*)(ws + carve((size_t)NATOMS * 4));
    int*   offs    = (int*)(ws + carve((size_t)(NATOMS + 1) * 4));
    int*   cursor  = (int*)(ws + carve((size_t)NATOMS * 4));
    int*   plist   = (int*)(ws + carve((size_t)NPAIRS * 4));

    hipMemsetAsync(cnt, 0, (size_t)NATOMS * 4, stream);

    k_hist<<<NPAIRS / 256, 256, 0, stream>>>(aidx, cnt);
    k_scan<<<1, 1024, 0, stream>>>(cnt, offs, cursor);
    k_scatter<<<NPAIRS / 256, 256, 0, stream>>>(aidx, cursor, plist);

    k_center<<<NATOMS / 4, 256, 0, stream>>>(spec, embc_W1, embc_b1, embc_g, embc_be,
                                             embc_W2, embc_b2, ccenter);
    k_table<<<(TBLN + 3) / 4, 256, 0, stream>>>(embn_W1, embn_b1, embn_g, embn_be,
                                                embn_W2, embn_b2, table);

    k_pair2<<<NPAIRS / 256, 256, 0, stream>>>(cart, aidx, spec, table, plist,
                                              outp, ang, radial, it0, neigh);

    // l=0: density(iter0) + oc_0 -> Sa
    k_dens_oc<false, false><<<NATOMS / 4, 256, 0, stream>>>(
        offs, ang, radial, it0, neigh, nullptr, ccenter, ccoeff + 0 * 1024,
        oc_W1 + 0 * 4096, oc_b1 + 0 * 64, oc_g + 0 * 64, oc_be + 0 * 64,
        oc_W2 + 0 * 512, oc_b2 + 0 * 8, Sa);
    // l=1: density(iter0 + Sa[neigh]) + oc_1 -> Sb = Sa + o
    k_dens_oc<true, true><<<NATOMS / 4, 256, 0, stream>>>(
        offs, ang, radial, it0, neigh, Sa, ccenter, ccoeff + 1 * 1024,
        oc_W1 + 1 * 4096, oc_b1 + 1 * 64, oc_g + 1 * 64, oc_be + 1 * 64,
        oc_W2 + 1 * 512, oc_b2 + 1 * 8, Sb);
    // l=2: density(iter0 + Sb[neigh]) + oc_2 -> Sa = Sb + o
    k_dens_oc<true, true><<<NATOMS / 4, 256, 0, stream>>>(
        offs, ang, radial, it0, neigh, Sb, ccenter, ccoeff + 2 * 1024,
        oc_W1 + 2 * 4096, oc_b1 + 2 * 64, oc_g + 2 * 64, oc_be + 2 * 64,
        oc_W2 + 2 * 512, oc_b2 + 2 * 8, Sa);
    // final: density(iter0 + Sa[neigh]) + out-MLP -> output
    k_dens_out<<<NATOMS / 4, 256, 0, stream>>>(
        offs, ang, radial, it0, neigh, Sa, ccenter, ccoeff + 3 * 1024, spec,
        out_W1, out_b1, out_g, out_be, out_W2, out_b2, outp + (size_t)NPAIRS * 3);
}